// Round 7
// baseline (21327.686 us; speedup 1.0000x reference)
//
#include <hip/hip_runtime.h>

#define B_SZ 2
#define SEQ 4162
#define M_REAL (B_SZ*SEQ)      // 8324
#define DM 1024
#define DI 2048
#define NH 16
#define HD 128
#define DIN 4240               // D_IN_PROJ
#define CONVD 2176
#define XBCW 2192              // CONVD + NH (xBC + dt columns)
#define QCH 64                 // scan chunk (LDS: 2*64*64*4 = 32 KB + 0.5 KB -> safe)
#define NCHS 66                // ceil(SEQ/QCH)

typedef float f32x4 __attribute__((ext_vector_type(4)));

__device__ __forceinline__ ushort f2bf(float f) {
  union { float f; unsigned u; } v; v.f = f;
  unsigned r = v.u + 0x7fffu + ((v.u >> 16) & 1u);
  return (ushort)(r >> 16);
}
__device__ __forceinline__ float bf2f(ushort u) {
  union { unsigned u; float f; } v; v.u = ((unsigned)u) << 16;
  return v.f;
}

// ---------------- naive f32 GEMM: C[M,N] = A[M,K] * W[N,K]^T --------------------
// mode: 0 = f32 store, 1 = f32 add, 2 = bf16 store
__global__ __launch_bounds__(256) void gemm_f32(const float* __restrict__ A,
  const float* __restrict__ W, void* __restrict__ Cv,
  int M, int N, int K, int ldc, int mode)
{
  __shared__ float As[64][17];
  __shared__ float Ws[64][17];
  const int tx = threadIdx.x & 15, ty = threadIdx.x >> 4;
  const int m0 = blockIdx.y * 64, n0 = blockIdx.x * 64;
  float acc[4][4] = {};
  for (int k0 = 0; k0 < K; k0 += 16) {
#pragma unroll
    for (int it = 0; it < 4; ++it) {
      int r = ty + 16*it;
      int gm = m0 + r;
      As[r][tx] = (gm < M) ? A[(size_t)gm*K + k0 + tx] : 0.f;
      int gn = n0 + r;
      Ws[r][tx] = (gn < N) ? W[(size_t)gn*K + k0 + tx] : 0.f;
    }
    __syncthreads();
#pragma unroll
    for (int kk = 0; kk < 16; ++kk) {
      float av[4], wv[4];
#pragma unroll
      for (int i = 0; i < 4; ++i) av[i] = As[ty*4 + i][kk];
#pragma unroll
      for (int j = 0; j < 4; ++j) wv[j] = Ws[tx*4 + j][kk];
#pragma unroll
      for (int i = 0; i < 4; ++i)
#pragma unroll
        for (int j = 0; j < 4; ++j) acc[i][j] += av[i]*wv[j];
    }
    __syncthreads();
  }
#pragma unroll
  for (int i = 0; i < 4; ++i) {
    int gm = m0 + ty*4 + i;
    if (gm >= M) continue;
#pragma unroll
    for (int j = 0; j < 4; ++j) {
      int gn = n0 + tx*4 + j;
      if (gn >= N) continue;
      size_t idx = (size_t)gm*ldc + gn;
      if (mode == 2)      ((ushort*)Cv)[idx] = f2bf(acc[i][j]);
      else if (mode == 1) ((float*)Cv)[idx] += acc[i][j];
      else                ((float*)Cv)[idx]  = acc[i][j];
    }
  }
}

__global__ void zero_kernel(float* __restrict__ p) { if (threadIdx.x == 0) p[0] = 0.f; }

__global__ void probe_kernel(float* __restrict__ o, float v) {
  if (threadIdx.x == 0) o[0] = v;
}

// ---------------- embed: from_rgb + concat + upsample + posemb ------------------
__global__ __launch_bounds__(256) void embed_kernel(const float* __restrict__ im8,
  const float* __restrict__ frw, const float* __restrict__ frb,
  const float* __restrict__ s0, const float* __restrict__ s1,
  const float* __restrict__ pos, float* __restrict__ x)
{
  int li = blockIdx.x, b = blockIdx.y, t = threadIdx.x;
  float* orow = x + ((size_t)b*SEQ + li)*DM;
  if (li == 0 || li == 65) {
    const float* s = (li == 0) ? s0 : s1;
    for (int d = t; d < DM; d += 256) orow[d] = s[d];
    return;
  }
  int i8; const float* pe = nullptr;
  if (li <= 64) i8 = li - 1;
  else {
    int j = li - 66;
    i8 = ((j >> 9) << 3) + ((j & 63) >> 3);
    pe = pos + (size_t)j*DM;
  }
  float c0 = im8[(b*64 + i8)*3 + 0];
  float c1 = im8[(b*64 + i8)*3 + 1];
  float c2 = im8[(b*64 + i8)*3 + 2];
  for (int d = t; d < DM; d += 256) {
    float v = c0*frw[d] + c1*frw[DM + d] + c2*frw[2*DM + d] + frb[d];
    if (pe) v += pe[d];
    orow[d] = v;
  }
}

// ---------------- layernorm (f32 out) -------------------------------------------
__global__ __launch_bounds__(256) void ln_kernel(const float* __restrict__ x,
  const float* __restrict__ w, const float* __restrict__ b, float* __restrict__ xn)
{
  int m = blockIdx.x, t = threadIdx.x;
  float* orow = xn + (size_t)m*DM;
  const float* xr = x + (size_t)m*DM;
  float v0=xr[t], v1=xr[t+256], v2=xr[t+512], v3=xr[t+768];
  float s = v0+v1+v2+v3;
  float q = v0*v0+v1*v1+v2*v2+v3*v3;
  int l = t & 63, wv = t >> 6;
#pragma unroll
  for (int o=32;o>0;o>>=1){ s += __shfl_down(s,o); q += __shfl_down(q,o); }
  __shared__ float rs[4], rq[4];
  if (l==0){ rs[wv]=s; rq[wv]=q; }
  __syncthreads();
  s = rs[0]+rs[1]+rs[2]+rs[3]; q = rq[0]+rq[1]+rq[2]+rq[3];
  float mean = s * (1.f/DM);
  float var  = q * (1.f/DM) - mean*mean;
  float rstd = rsqrtf(var + 1e-5f);
  orow[t]     = (v0-mean)*rstd*w[t]     + b[t];
  orow[t+256] = (v1-mean)*rstd*w[t+256] + b[t+256];
  orow[t+512] = (v2-mean)*rstd*w[t+512] + b[t+512];
  orow[t+768] = (v3-mean)*rstd*w[t+768] + b[t+768];
}

// ---------------- dt = softplus(xBCdt[...,2176+h] + bias), dA = exp(dt*A) -------
__global__ void dt_kernel(const float* __restrict__ xbc, const float* __restrict__ dtb,
  const float* __restrict__ alog, float* __restrict__ dta, float* __restrict__ dAa)
{
  int idx = blockIdx.x*256 + threadIdx.x;
  if (idx >= M_REAL*NH) return;
  int m = idx >> 4, h = idx & 15;
  float raw = xbc[(size_t)m*XBCW + CONVD + h] + dtb[h];
  float dt = (raw > 20.f) ? raw : log1pf(expf(raw));
  float A = -expf(alog[h]);
  dta[idx] = dt;
  dAa[idx] = expf(dt*A);
}

// ---------------- depthwise causal conv (k=4) + silu, f32 in / bf16 out ---------
__global__ __launch_bounds__(256) void conv_kernel(const float* __restrict__ xbc,
  const float* __restrict__ cw, const float* __restrict__ cb, ushort* __restrict__ out)
{
  int ch = blockIdx.x*256 + threadIdx.x;
  int m = blockIdx.y;
  if (ch >= CONVD) return;
  int l = m % SEQ;
  float acc = cb[ch];
#pragma unroll
  for (int k = 0; k < 4; ++k) {
    int ls = l - 3 + k;
    if (ls >= 0) acc += xbc[(size_t)(m - 3 + k)*XBCW + ch] * cw[ch*4 + k];
  }
  out[(size_t)m*CONVD + ch] = f2bf(acc / (1.f + expf(-acc)));
}

// ---------------- sequential SSM scan: one block per (b,h), full SEQ ------------
// LDS: 2*QCH*64*4 = 32 KB + 0.5 KB  (QCH=64 -> under the 64 KB limit)
__global__ __launch_bounds__(256) void ssm_seq(const ushort* __restrict__ cvo,
  const float* __restrict__ dta, const float* __restrict__ dAa, ushort* __restrict__ ybuf)
{
  __shared__ float Bl[QCH*64];
  __shared__ float Cl[QCH*64];
  __shared__ float dtl[QCH], dAl[QCH];
  int bh = blockIdx.x, b = bh >> 4, h = bh & 15;
  int t = threadIdx.x;
  int p = t >> 1, n0 = (t & 1)*32;
  f32x4 hst[8];
  f32x4 z4 = {0.f,0.f,0.f,0.f};
#pragma unroll
  for (int i=0;i<8;++i) hst[i] = z4;
  for (int c = 0; c < NCHS; ++c) {
    int l0 = c*QCH;
    int Lc = SEQ - l0; if (Lc > QCH) Lc = QCH;
    size_t rowbase = (size_t)(b*SEQ + l0);
    __syncthreads();   // protect LDS from previous chunk's readers
    for (int e = t; e < QCH*64; e += 256) {
      int s = e >> 6, n = e & 63;
      if (s < Lc) {
        Bl[e] = bf2f(cvo[(rowbase + s)*CONVD + 2048 + n]);
        Cl[e] = bf2f(cvo[(rowbase + s)*CONVD + 2112 + n]);
      }
    }
    if (t < Lc) { dtl[t] = dta[(rowbase+t)*NH + h]; dAl[t] = dAa[(rowbase+t)*NH + h]; }
    __syncthreads();
    const ushort* xcol = cvo + rowbase*CONVD + h*HD + p;
    for (int s = 0; s < Lc; ++s) {
      float dtx = dtl[s] * bf2f(xcol[(size_t)s*CONVD]);
      float da = dAl[s];
      const f32x4* brow = (const f32x4*)&Bl[s*64 + n0];
      const f32x4* crow = (const f32x4*)&Cl[s*64 + n0];
      f32x4 yv = {0.f,0.f,0.f,0.f};
#pragma unroll
      for (int i=0;i<8;++i) {
        hst[i] = hst[i]*da + brow[i]*dtx;
        yv += hst[i]*crow[i];
      }
      float yp = yv[0]+yv[1]+yv[2]+yv[3];
      yp += __shfl_xor(yp, 1);
      if ((t & 1) == 0) ybuf[(rowbase + s)*DI + h*HD + p] = f2bf(yp);
    }
  }
}

// ---------------- gate: (y + xs*D) * silu(z), RMSNorm -> f32 --------------------
__global__ __launch_bounds__(256) void gate_kernel(const ushort* __restrict__ ybuf,
  const ushort* __restrict__ cvo, const ushort* __restrict__ zbuf,
  const float* __restrict__ Dp, const float* __restrict__ rmsw, float* __restrict__ vb)
{
  int m = blockIdx.x, t = threadIdx.x;
  float* orow = vb + (size_t)m*DI;
  float vv[8]; float q = 0.f;
#pragma unroll
  for (int i=0;i<8;++i) {
    int ch = t + 256*i;
    float xs = bf2f(cvo[(size_t)m*CONVD + ch]);
    float y  = bf2f(ybuf[(size_t)m*DI + ch]) + xs*Dp[ch>>7];
    float z  = bf2f(zbuf[(size_t)m*DI + ch]);
    float g  = z / (1.f + expf(-z));
    float vg = y*g;
    vv[i] = vg; q += vg*vg;
  }
  int l = t&63, wv = t>>6;
#pragma unroll
  for (int o=32;o>0;o>>=1) q += __shfl_down(q,o);
  __shared__ float rq[4];
  if (l==0) rq[wv]=q;
  __syncthreads();
  q = rq[0]+rq[1]+rq[2]+rq[3];
  float r = rsqrtf(q*(1.f/DI) + 1e-5f);
#pragma unroll
  for (int i=0;i<8;++i){ int ch = t+256*i; orow[ch] = vv[i]*r*rmsw[ch]; }
}

// ---------------- head: to_rgb + loss (f32 output!) -----------------------------
__global__ __launch_bounds__(256) void head_kernel(const float* __restrict__ x,
  const float* __restrict__ w, const float* __restrict__ bias, const float* __restrict__ im64,
  float* __restrict__ outy, float* __restrict__ lacc)
{
  int j = blockIdx.x, b = blockIdx.y, t = threadIdx.x;
  const float* xr = x + ((size_t)(b*SEQ + 66 + j))*DM;
  float p0=0.f,p1=0.f,p2=0.f;
  for (int d = t; d < DM; d += 256) {
    float xv = xr[d];
    p0 += xv*w[d*3+0]; p1 += xv*w[d*3+1]; p2 += xv*w[d*3+2];
  }
  int l = t & 63, wv = t >> 6;
#pragma unroll
  for (int o = 32; o > 0; o >>= 1) {
    p0 += __shfl_down(p0,o); p1 += __shfl_down(p1,o); p2 += __shfl_down(p2,o);
  }
  __shared__ float red[4][3];
  if (l == 0) { red[wv][0]=p0; red[wv][1]=p1; red[wv][2]=p2; }
  __syncthreads();
  if (t == 0) {
    float y0 = red[0][0]+red[1][0]+red[2][0]+red[3][0] + bias[0];
    float y1 = red[0][1]+red[1][1]+red[2][1]+red[3][1] + bias[1];
    float y2 = red[0][2]+red[1][2]+red[2][2]+red[3][2] + bias[2];
    size_t o3 = ((size_t)b*4096 + j)*3;
    float e0 = y0 - im64[o3], e1 = y1 - im64[o3+1], e2 = y2 - im64[o3+2];
    outy[o3]   = y0;
    outy[o3+1] = y1;
    outy[o3+2] = y2;
    atomicAdd(lacc, e0*e0+e1*e1+e2*e2);
  }
}

__global__ void loss_final(const float* __restrict__ lacc, float* __restrict__ outy)
{
  if (threadIdx.x == 0 && blockIdx.x == 0)
    outy[(size_t)B_SZ*4096*3] = lacc[0] * (1.f/((float)B_SZ*4096.f*3.f));
}

// ================================================================================
extern "C" void kernel_launch(void* const* d_in, const int* in_sizes, int n_in,
                              void* d_out, int out_size, void* d_ws, size_t ws_size,
                              hipStream_t stream)
{
  (void)in_sizes; (void)n_in; (void)out_size;
  const float* im8   = (const float*)d_in[0];
  const float* im64  = (const float*)d_in[1];
  const float* frw   = (const float*)d_in[2];
  const float* frb   = (const float*)d_in[3];
  const float* trw   = (const float*)d_in[4];
  const float* trb   = (const float*)d_in[5];
  const float* s0    = (const float*)d_in[6];
  const float* s1    = (const float*)d_in[7];
  const float* pos   = (const float*)d_in[8];
  const float* lnw   = (const float*)d_in[9];
  const float* lnb   = (const float*)d_in[10];
  const float* w1    = (const float*)d_in[11];
  const float* cw    = (const float*)d_in[12];
  const float* cb    = (const float*)d_in[13];
  const float* dtb   = (const float*)d_in[14];
  const float* alog  = (const float*)d_in[15];
  const float* Dp    = (const float*)d_in[16];
  const float* rmsw  = (const float*)d_in[17];
  const float* w2    = (const float*)d_in[18];

  // Arena ~213 MB with overlays; explicit ws_size check (probe fallback).
  char* ws = (char*)d_ws;
  size_t off = 0;
  auto take = [&](size_t bytes) { char* p = ws + off; off = (off + bytes + 255) & ~(size_t)255; return p; };
  float*  x     = (float*)take((size_t)M_REAL*DM*4);       // 34.1 MB, persistent
  // RA: xn (f32, ln->gemms) overlays ybuf (bf16, scan->gate); equal sizes
  char*   RA    = take((size_t)M_REAL*DM*4);               // 34.1 MB
  float*  xn    = (float*)RA;
  ushort* ybuf  = (ushort*)RA;
  ushort* zbuf  = (ushort*)take((size_t)M_REAL*DI*2);      // 34.1 MB (M_REAL x 2048 bf16)
  // RB: xBCdt (f32, gemm->conv/dt) overlays vb (f32, gate->gemm2)
  char*   RB    = take((size_t)M_REAL*XBCW*4);             // 73.0 MB
  float*  xbc   = (float*)RB;
  float*  vb    = (float*)RB;
  ushort* cvo   = (ushort*)take((size_t)M_REAL*CONVD*2);   // 36.2 MB
  float*  dta   = (float*)take((size_t)M_REAL*NH*4);       //  0.53 MB
  float*  dAa   = (float*)take((size_t)M_REAL*NH*4);       //  0.53 MB
  float*  lacc  = (float*)take(256);
  size_t needed = off;

  if (needed > ws_size) {
    // Diagnostic: absmax will read ~= ws_size in MB.
    probe_kernel<<<1, 64, 0, stream>>>((float*)d_out, (float)(ws_size >> 20));
    return;
  }

  zero_kernel<<<1, 64, 0, stream>>>(lacc);
  embed_kernel<<<dim3(SEQ, B_SZ), 256, 0, stream>>>(im8, frw, frb, s0, s1, pos, x);

  for (int L = 0; L < 4; ++L) {
    ln_kernel<<<M_REAL, 256, 0, stream>>>(x, lnw + L*DM, lnb + L*DM, xn);
    // z columns (0..2047) -> bf16 zbuf
    gemm_f32<<<dim3(DI/64, (M_REAL+63)/64), 256, 0, stream>>>(
        xn, w1 + (size_t)L*DIN*DM, zbuf, M_REAL, DI, DM, DI, 2);
    // xBC + dt columns (2048..4239) -> f32 xbc
    gemm_f32<<<dim3((XBCW+63)/64, (M_REAL+63)/64), 256, 0, stream>>>(
        xn, w1 + (size_t)L*DIN*DM + (size_t)2048*DM, xbc, M_REAL, XBCW, DM, XBCW, 0);
    dt_kernel<<<(M_REAL*NH + 255)/256, 256, 0, stream>>>(
        xbc, dtb + L*NH, alog + L*NH, dta, dAa);
    conv_kernel<<<dim3((CONVD+255)/256, M_REAL), 256, 0, stream>>>(
        xbc, cw + (size_t)L*CONVD*4, cb + (size_t)L*CONVD, cvo);
    ssm_seq<<<32, 256, 0, stream>>>(cvo, dta, dAa, ybuf);
    gate_kernel<<<M_REAL, 256, 0, stream>>>(ybuf, cvo, zbuf, Dp + L*NH, rmsw + (size_t)L*DI, vb);
    gemm_f32<<<dim3(DM/64, (M_REAL+63)/64), 256, 0, stream>>>(
        vb, w2 + (size_t)L*DM*DI, x, M_REAL, DM, DI, DM, 1);
  }

  head_kernel<<<dim3(4096, B_SZ), 256, 0, stream>>>(x, trw, trb, im64, (float*)d_out, lacc);
  loss_final<<<1, 64, 0, stream>>>(lacc, (float*)d_out);
}